// Round 7
// baseline (55.499 us; speedup 1.0000x reference)
//
#include <hip/hip_runtime.h>

// skipgram negative-sampling loss, MI355X — round 7.
// Concurrency attack: 4 waves per row (5 negs each), readfirstlane-forced
// scalar index loads (s_load + SGPR-base gathers), partials to ws, and a
// single-block stage2 (plain store -> no atomic, no memset; 2-dispatch graph).
// R5 proved the wall is not bytes (fp16 halved FETCH, time constant); R6
// proved wave-count moves it (2x waves -> 41->~31us stage1). Push same lever.

constexpr int DIM  = 128;
constexpr int KNEG = 20;
constexpr int SPLIT = 4;                       // waves per row
constexpr int NPW  = KNEG / SPLIT;             // 5 negs per wave

__device__ __forceinline__ float log_sigmoid(float x) {
    // stable: min(x,0) - log1p(exp(-|x|))
    return fminf(x, 0.0f) - log1pf(__expf(-fabsf(x)));
}

// ---------- stage 1: per-(row, quarter-K) partial dots ----------
// wave gw: b = gw>>2, c = gw&3. All 4 waves of a row live in one block.
// b,c forced to SGPRs -> v_neg/u_pos/v_pos reads become s_load; every gather
// is SGPR-base + lane*8.
__global__ __launch_bounds__(256) void skipgram_stage1(
    const float* __restrict__ u_emb, const float* __restrict__ v_emb,
    const int* __restrict__ u_pos, const int* __restrict__ v_pos,
    const int* __restrict__ v_neg,
    float* __restrict__ pos_arr, float* __restrict__ negp_arr, int B)
{
    const int lane  = threadIdx.x & 63;
    const int wslot = threadIdx.x >> 6;          // uniform within a wave
    const int gw    = blockIdx.x * 4 + wslot;
    const int b     = __builtin_amdgcn_readfirstlane(gw >> 2);
    const int c     = __builtin_amdgcn_readfirstlane(gw & 3);
    if (b >= B) return;

    // uniform scalar loads
    const int up = u_pos[b];
    const int kb = b * KNEG + c * NPW;
    int idx[NPW];
    #pragma unroll
    for (int j = 0; j < NPW; ++j) idx[j] = v_neg[kb + j];

    // gathers: one 512B row per VMEM instr, float2 per lane
    const float2 uu = reinterpret_cast<const float2*>(u_emb + (size_t)up * DIM)[lane];

    float2 vv = make_float2(0.0f, 0.0f);
    if (c == 0) {                                // uniform branch
        const int vp = v_pos[b];
        vv = reinterpret_cast<const float2*>(v_emb + (size_t)vp * DIM)[lane];
    }

    float2 nv[NPW];
    #pragma unroll
    for (int j = 0; j < NPW; ++j)
        nv[j] = reinterpret_cast<const float2*>(v_emb + (size_t)idx[j] * DIM)[lane];

    // compute
    float pos = fmaf(uu.x, vv.x, uu.y * vv.y);   // zero when c!=0
    float ax = 0.0f, ay = 0.0f;
    #pragma unroll
    for (int j = 0; j < NPW; ++j) { ax += nv[j].x; ay += nv[j].y; }
    float negp = fmaf(uu.x, ax, uu.y * ay);

    // 64-lane butterfly (both dots together)
    #pragma unroll
    for (int off = 32; off; off >>= 1) {
        pos  += __shfl_xor(pos,  off);
        negp += __shfl_xor(negp, off);
    }

    if (lane == 0) {
        negp_arr[c * B + b] = negp;              // c-major: coalesced in stage2
        if (c == 0) pos_arr[b] = pos;
    }
}

// ---------- stage 2: one block, logsigmoid + full reduction, plain store ----------
__global__ __launch_bounds__(1024) void skipgram_stage2(
    const float* __restrict__ pos_arr, const float* __restrict__ negp_arr,
    float* __restrict__ out, int B, float neg_inv_b)
{
    float acc = 0.0f;
    for (int r = threadIdx.x; r < B; r += 1024) {
        float pos = pos_arr[r];
        float neg = negp_arr[r] + negp_arr[B + r] + negp_arr[2 * B + r] + negp_arr[3 * B + r];
        acc += log_sigmoid(pos) + log_sigmoid(-neg);
    }

    #pragma unroll
    for (int off = 32; off; off >>= 1) acc += __shfl_xor(acc, off);

    __shared__ float wsum[16];
    const int lane = threadIdx.x & 63;
    const int w    = threadIdx.x >> 6;
    if (lane == 0) wsum[w] = acc;
    __syncthreads();
    if (threadIdx.x == 0) {
        float s = 0.0f;
        #pragma unroll
        for (int i = 0; i < 16; ++i) s += wsum[i];
        out[0] = s * neg_inv_b;                  // overwrite: no memset needed
    }
}

// ---------- fallback: single-kernel f32 if ws too small ----------
__global__ __launch_bounds__(256) void skipgram_f32_kernel(
    const float* __restrict__ u_emb, const float* __restrict__ v_emb,
    const int* __restrict__ u_pos, const int* __restrict__ v_pos,
    const int* __restrict__ v_neg, float* __restrict__ out,
    int B, float neg_inv_b)
{
    const int lane  = threadIdx.x & 63;
    const int wslot = threadIdx.x >> 6;
    const int row   = blockIdx.x * 4 + wslot;

    float contrib = 0.0f;
    if (row < B) {
        const int up = u_pos[row];
        const int vp = v_pos[row];
        int idx[KNEG];
        #pragma unroll
        for (int k = 0; k < KNEG; ++k) idx[k] = v_neg[row * KNEG + k];
        const float2 uu = reinterpret_cast<const float2*>(u_emb + (size_t)up * DIM)[lane];
        const float2 vv = reinterpret_cast<const float2*>(v_emb + (size_t)vp * DIM)[lane];
        float pos = fmaf(uu.x, vv.x, uu.y * vv.y);
        float ax = 0.0f, ay = 0.0f;
        #pragma unroll
        for (int k = 0; k < KNEG; ++k) {
            float2 nv = reinterpret_cast<const float2*>(v_emb + (size_t)idx[k] * DIM)[lane];
            ax += nv.x; ay += nv.y;
        }
        float neg = fmaf(uu.x, ax, uu.y * ay);
        #pragma unroll
        for (int off = 32; off; off >>= 1) {
            pos += __shfl_xor(pos, off);
            neg += __shfl_xor(neg, off);
        }
        if (lane != 0) { pos = 0.0f; neg = 0.0f; }
        contrib = (lane == 0) ? (log_sigmoid(pos) + log_sigmoid(-neg)) : 0.0f;
    }

    __shared__ float wsum[4];
    if (lane == 0) wsum[wslot] = contrib;
    __syncthreads();
    if (threadIdx.x == 0) {
        float s = 0.0f;
        #pragma unroll
        for (int w = 0; w < 4; ++w) s += wsum[w];
        atomicAdd(out, s * neg_inv_b);
    }
}

extern "C" void kernel_launch(void* const* d_in, const int* in_sizes, int n_in,
                              void* d_out, int out_size, void* d_ws, size_t ws_size,
                              hipStream_t stream) {
    const float* u_emb = (const float*)d_in[0];
    const float* v_emb = (const float*)d_in[1];
    const int*   u_pos = (const int*)d_in[2];
    const int*   v_pos = (const int*)d_in[3];
    const int*   v_neg = (const int*)d_in[4];
    float* out = (float*)d_out;

    const int B = in_sizes[2];                   // 16384

    const size_t needed = (size_t)(1 + SPLIT) * B * sizeof(float);
    if (ws_size >= needed) {
        float* pos_arr  = (float*)d_ws;
        float* negp_arr = pos_arr + B;

        const int blocks1 = B;                   // 4 waves/block, 4 waves/row
        skipgram_stage1<<<blocks1, 256, 0, stream>>>(
            u_emb, v_emb, u_pos, v_pos, v_neg, pos_arr, negp_arr, B);

        skipgram_stage2<<<1, 1024, 0, stream>>>(
            pos_arr, negp_arr, out, B, -1.0f / (float)B);
    } else {
        hipMemsetAsync(out, 0, sizeof(float), stream);
        const int blocks = (B + 3) / 4;
        skipgram_f32_kernel<<<blocks, 256, 0, stream>>>(
            u_emb, v_emb, u_pos, v_pos, v_neg, out, B, -1.0f / (float)B);
    }
}

// Round 8
// 35.062 us; speedup vs baseline: 1.5829x; 1.5829x over previous
//
#include <hip/hip_runtime.h>

// skipgram negative-sampling loss, MI355X — round 8.
// Core change: async global->LDS gathers (__builtin_amdgcn_global_load_lds,
// size=16) so outstanding loads are NOT capped by the register allocator
// (VGPR 28-52 in R2-R7 => compiler never kept >~6 data loads in flight).
// One wave per (row-pair, K-half): lanes 0-31 = row 2p, lanes 32-63 = row 2p+1;
// one size=16 instruction = 1KB = both rows' 512B chunks. 10 async loads/wave
// all in flight (vmcnt-tracked, zero dest VGPRs). u/v rows -> registers.
// Pair's two waves share a block: combine K-halves via LDS, one plain-store
// per-block loss; tiny stage2 reduces 8192 floats. 2 dispatches, no atomics.

constexpr int DIM  = 128;
constexpr int KNEG = 20;
constexpr int NPW  = 10;                 // negs per wave (K split across 2 waves)

__device__ __forceinline__ float log_sigmoid(float x) {
    // stable: min(x,0) - log1p(exp(-|x|))
    return fminf(x, 0.0f) - log1pf(__expf(-fabsf(x)));
}

typedef __attribute__((address_space(3))) unsigned int       lds_uint;
typedef const __attribute__((address_space(1))) unsigned int glob_uint;

// ---------- stage 1: one block = one row-pair (2 waves, c = K-half) ----------
__global__ __launch_bounds__(128) void skipgram_stage1(
    const float* __restrict__ u_emb, const float* __restrict__ v_emb,
    const int* __restrict__ u_pos, const int* __restrict__ v_pos,
    const int* __restrict__ v_neg, float* __restrict__ block_loss, int B)
{
    __shared__ float lds_negs[2][NPW * 256];   // [wave c][j-th 1KB chunk: 512B rowA | 512B rowB]
    __shared__ float neg1_sh[2];               // wave c=1 partials for rowA, rowB

    const int lane  = threadIdx.x & 63;
    const int c     = __builtin_amdgcn_readfirstlane(threadIdx.x >> 6);  // 0 or 1
    const int rowA  = blockIdx.x * 2;
    const int rowB  = rowA + 1;
    const int half  = lane >> 5;               // 0: serve rowA, 1: serve rowB
    const int l32   = lane & 31;

    // ---- uniform index loads (scalar path) ----
    const int upA = u_pos[rowA], upB = u_pos[rowB];
    int idxA[NPW], idxB[NPW];
    #pragma unroll
    for (int j = 0; j < NPW; ++j) {
        idxA[j] = v_neg[rowA * KNEG + c * NPW + j];
        idxB[j] = v_neg[rowB * KNEG + c * NPW + j];
    }

    // ---- async gathers: 10 x (1KB = both rows' 512B) all in flight ----
    float* lbase = &lds_negs[c][0];
    #pragma unroll
    for (int j = 0; j < NPW; ++j) {
        const float* g = (half == 0)
            ? (v_emb + (size_t)idxA[j] * DIM + l32 * 4)
            : (v_emb + (size_t)idxB[j] * DIM + l32 * 4);
        // HW semantics: LDS dest = wave-uniform base + lane*16; global src per-lane.
        __builtin_amdgcn_global_load_lds((glob_uint*)g,
                                         (lds_uint*)(lbase + j * 256), 16, 0, 0);
    }

    // ---- register loads for u (and v for c==0), pair-style float4 ----
    const float* urow = (half == 0) ? (u_emb + (size_t)upA * DIM)
                                    : (u_emb + (size_t)upB * DIM);
    const float4 uu = *reinterpret_cast<const float4*>(urow + l32 * 4);

    float4 vv = make_float4(0.0f, 0.0f, 0.0f, 0.0f);
    if (c == 0) {                              // wave-uniform branch
        const int vpA = v_pos[rowA], vpB = v_pos[rowB];
        const float* vrow = (half == 0) ? (v_emb + (size_t)vpA * DIM)
                                        : (v_emb + (size_t)vpB * DIM);
        vv = *reinterpret_cast<const float4*>(vrow + l32 * 4);
    }

    float pos = fmaf(uu.x, vv.x, fmaf(uu.y, vv.y, fmaf(uu.z, vv.z, uu.w * vv.w)));

    // ---- drain the async loads, then accumulate from LDS ----
    asm volatile("s_waitcnt vmcnt(0)" ::: "memory");
    __builtin_amdgcn_sched_barrier(0);

    float ax = 0.0f, ay = 0.0f, az = 0.0f, aw = 0.0f;
    #pragma unroll
    for (int j = 0; j < NPW; ++j) {
        // lane l wrote its own 16B at byte l*16 -> read it back: float offset lane*4
        float4 nv = *reinterpret_cast<const float4*>(&lds_negs[c][j * 256 + lane * 4]);
        ax += nv.x; ay += nv.y; az += nv.z; aw += nv.w;
    }
    float neg = fmaf(uu.x, ax, fmaf(uu.y, ay, fmaf(uu.z, az, uu.w * aw)));

    // ---- butterfly within each half-wave; lane0 = rowA, lane32 = rowB ----
    #pragma unroll
    for (int off = 16; off; off >>= 1) {
        pos += __shfl_xor(pos, off);
        neg += __shfl_xor(neg, off);
    }

    if (c == 1 && l32 == 0) neg1_sh[half] = neg;   // lane0 -> [0]=rowA, lane32 -> [1]=rowB
    __syncthreads();

    float bl = 0.0f;
    if (c == 0 && l32 == 0) {
        float negT = neg + neg1_sh[half];
        bl = log_sigmoid(pos) + log_sigmoid(-negT);
    }
    bl += __shfl_xor(bl, 32);                  // lane0 of wave0: lossA + lossB
    if (c == 0 && lane == 0) block_loss[blockIdx.x] = bl;
}

// ---------- stage 2: reduce 8192 per-block losses (32 KB), plain store ----------
__global__ __launch_bounds__(1024) void skipgram_stage2(
    const float* __restrict__ block_loss, float* __restrict__ out,
    int n, float neg_inv_b)
{
    float acc = 0.0f;
    for (int i = threadIdx.x; i < n; i += 1024) acc += block_loss[i];

    #pragma unroll
    for (int off = 32; off; off >>= 1) acc += __shfl_xor(acc, off);

    __shared__ float wsum[16];
    const int lane = threadIdx.x & 63;
    const int w    = threadIdx.x >> 6;
    if (lane == 0) wsum[w] = acc;
    __syncthreads();
    if (threadIdx.x == 0) {
        float s = 0.0f;
        #pragma unroll
        for (int i = 0; i < 16; ++i) s += wsum[i];
        out[0] = s * neg_inv_b;                // overwrite: no memset needed
    }
}

// ---------- fallback: single-kernel f32 if ws too small ----------
__global__ __launch_bounds__(256) void skipgram_f32_kernel(
    const float* __restrict__ u_emb, const float* __restrict__ v_emb,
    const int* __restrict__ u_pos, const int* __restrict__ v_pos,
    const int* __restrict__ v_neg, float* __restrict__ out,
    int B, float neg_inv_b)
{
    const int lane  = threadIdx.x & 63;
    const int wslot = threadIdx.x >> 6;
    const int row   = blockIdx.x * 4 + wslot;

    float contrib = 0.0f;
    if (row < B) {
        const int up = u_pos[row];
        const int vp = v_pos[row];
        int idx[KNEG];
        #pragma unroll
        for (int k = 0; k < KNEG; ++k) idx[k] = v_neg[row * KNEG + k];
        const float2 uu = reinterpret_cast<const float2*>(u_emb + (size_t)up * DIM)[lane];
        const float2 vv = reinterpret_cast<const float2*>(v_emb + (size_t)vp * DIM)[lane];
        float pos = fmaf(uu.x, vv.x, uu.y * vv.y);
        float ax = 0.0f, ay = 0.0f;
        #pragma unroll
        for (int k = 0; k < KNEG; ++k) {
            float2 nv = reinterpret_cast<const float2*>(v_emb + (size_t)idx[k] * DIM)[lane];
            ax += nv.x; ay += nv.y;
        }
        float neg = fmaf(uu.x, ax, uu.y * ay);
        #pragma unroll
        for (int off = 32; off; off >>= 1) {
            pos += __shfl_xor(pos, off);
            neg += __shfl_xor(neg, off);
        }
        contrib = (lane == 0) ? (log_sigmoid(pos) + log_sigmoid(-neg)) : 0.0f;
    }

    __shared__ float wsum[4];
    if (lane == 0) wsum[wslot] = contrib;
    __syncthreads();
    if (threadIdx.x == 0) {
        float s = 0.0f;
        #pragma unroll
        for (int w = 0; w < 4; ++w) s += wsum[w];
        atomicAdd(out, s * neg_inv_b);
    }
}

extern "C" void kernel_launch(void* const* d_in, const int* in_sizes, int n_in,
                              void* d_out, int out_size, void* d_ws, size_t ws_size,
                              hipStream_t stream) {
    const float* u_emb = (const float*)d_in[0];
    const float* v_emb = (const float*)d_in[1];
    const int*   u_pos = (const int*)d_in[2];
    const int*   v_pos = (const int*)d_in[3];
    const int*   v_neg = (const int*)d_in[4];
    float* out = (float*)d_out;

    const int B     = in_sizes[2];             // 16384
    const int pairs = B / 2;                   // 8192

    const size_t needed = (size_t)pairs * sizeof(float);
    if (ws_size >= needed && (B % 2) == 0) {
        float* block_loss = (float*)d_ws;

        skipgram_stage1<<<pairs, 128, 0, stream>>>(
            u_emb, v_emb, u_pos, v_pos, v_neg, block_loss, B);

        skipgram_stage2<<<1, 1024, 0, stream>>>(
            block_loss, out, pairs, -1.0f / (float)B);
    } else {
        hipMemsetAsync(out, 0, sizeof(float), stream);
        const int blocks = (B + 3) / 4;
        skipgram_f32_kernel<<<blocks, 256, 0, stream>>>(
            u_emb, v_emb, u_pos, v_pos, v_neg, out, B, -1.0f / (float)B);
    }
}